// Round 5
// baseline (486.028 us; speedup 1.0000x reference)
//
#include <hip/hip_runtime.h>

#define NTHREADS 256
#define EPT      8              // elements per thread
#define CHUNK    (NTHREADS*EPT) // 2048 elements per block
#define ROWS     16

#define C_TREND   0.6f
#define C_DETAIL  0.85f
#define C_SPIKE_T 3.5f
#define C_SPIKE_D 0.35f
#define C_EPS     1e-6f

typedef float vfloat4 __attribute__((ext_vector_type(4)));

__device__ __forceinline__ float reflect_load(const float* __restrict__ rp, int g, int L) {
    if (g < 0) g = -g;
    else if (g >= L) g = 2 * L - 2 - g;
    return rp[g];
}

// Deterministic block reduce of (s,s2); all threads receive the totals.
__device__ __forceinline__ void blk_reduce2(double& s, double& s2) {
    #pragma unroll
    for (int off = 32; off > 0; off >>= 1) {
        s  += __shfl_xor(s, off);
        s2 += __shfl_xor(s2, off);
    }
    __shared__ double lds[8];
    int wid = threadIdx.x >> 6, lane = threadIdx.x & 63;
    __syncthreads();                       // guard lds reuse across calls
    if (lane == 0) { lds[2*wid] = s; lds[2*wid+1] = s2; }
    __syncthreads();
    s  = lds[0] + lds[2] + lds[4] + lds[6];
    s2 = lds[1] + lds[3] + lds[5] + lds[7];
}

// Release-store this block's partial; the last block of the row (atomic
// ticket) acquire-reads all bpr partials IN FIXED ORDER and writes thr.
__device__ __forceinline__ void partial_and_finalize(
    double s, double s2,
    double2* __restrict__ prow,   // row-base of partials
    int* __restrict__ cnt,        // &counter[row]
    float* __restrict__ thr_out,  // &thr[row]
    int slot, int bpr, int L) {
    blk_reduce2(s, s2);
    __shared__ int last;
    if (threadIdx.x == 0) {
        double* pd = reinterpret_cast<double*>(prow + slot);
        __hip_atomic_store(pd + 0, s,  __ATOMIC_RELAXED, __HIP_MEMORY_SCOPE_AGENT);
        __hip_atomic_store(pd + 1, s2, __ATOMIC_RELAXED, __HIP_MEMORY_SCOPE_AGENT);
        int old = __hip_atomic_fetch_add(cnt, 1, __ATOMIC_ACQ_REL, __HIP_MEMORY_SCOPE_AGENT);
        last = (old == bpr - 1);
    }
    __syncthreads();
    if (!last) return;
    double a = 0.0, b = 0.0;
    for (int i = threadIdx.x; i < bpr; i += NTHREADS) {   // fixed order
        const double* pd = reinterpret_cast<const double*>(prow + i);
        a += __hip_atomic_load(pd + 0, __ATOMIC_RELAXED, __HIP_MEMORY_SCOPE_AGENT);
        b += __hip_atomic_load(pd + 1, __ATOMIC_RELAXED, __HIP_MEMORY_SCOPE_AGENT);
    }
    blk_reduce2(a, b);
    if (threadIdx.x == 0) {
        double n = (double)L;
        double var = (b - a * a / n) / (n - 1.0);
        float stdv = (float)sqrt(fmax(var, 0.0));
        *thr_out = fmaxf(stdv, C_EPS) * C_SPIKE_T;
    }
}

// scalar (boundary) pass-1 output at logical position p (reflect-indexed)
__device__ float xp1_scalar(const float* __restrict__ rp, int L, int p, float thr) {
    if (p < 0) p = -p;
    else if (p >= L) p = 2 * L - 2 - p;
    float s5 = 0.f, s11 = 0.f;
    #pragma unroll
    for (int k = -5; k <= 5; ++k) {
        float v = reflect_load(rp, p + k, L);
        s11 += v;
        if (k >= -2 && k <= 2) s5 += v;
    }
    float local = s5 * 0.2f;
    float trend = s11 * (1.0f / 11.0f);
    float r = rp[p] - local;
    r = (fabsf(r) > thr) ? r * C_SPIKE_D : r;
    return (1.0f - C_TREND) * local + C_TREND * trend + C_DETAIL * r;
}

// ---- K1: pass-1 residual partials -> thr1 (last-block finalize) ----
__global__ __launch_bounds__(NTHREADS) void k1_reduce(
    const float* __restrict__ x, double2* __restrict__ partials1,
    int* __restrict__ cnt1, float* __restrict__ thr1, int L, int bpr) {
    int row = blockIdx.x / bpr, chunk = blockIdx.x % bpr;
    const float* rp = x + (size_t)row * L;
    int o = chunk * CHUNK + threadIdx.x * EPT;

    float w[16];
    if (o >= 4 && o + 12 <= L) {
        const float4* p = reinterpret_cast<const float4*>(rp + o - 4);
        #pragma unroll
        for (int j = 0; j < 4; ++j) {
            float4 v = p[j];
            w[4*j+0] = v.x; w[4*j+1] = v.y; w[4*j+2] = v.z; w[4*j+3] = v.w;
        }
    } else {
        #pragma unroll
        for (int j = 0; j < 16; ++j) w[j] = reflect_load(rp, o - 4 + j, L);
    }
    double s = 0.0, s2 = 0.0;
    float s5 = w[2] + w[3] + w[4] + w[5] + w[6];
    #pragma unroll
    for (int k = 0; k < EPT; ++k) {
        float r = w[4 + k] - s5 * 0.2f;
        s += (double)r;
        s2 = fma((double)r, (double)r, s2);
        if (k < EPT - 1) s5 += w[7 + k] - w[2 + k];
    }
    partial_and_finalize(s, s2, partials1 + (size_t)row * bpr,
                         &cnt1[row], &thr1[row], chunk, bpr, L);
}

// ---- K2: recompute pass-1 output in-register, pass-2 residual partials -> thr2 ----
__global__ __launch_bounds__(NTHREADS) void k2_reduce(
    const float* __restrict__ x, const float* __restrict__ thr1,
    double2* __restrict__ partials2, int* __restrict__ cnt2,
    float* __restrict__ thr2, int L, int bpr) {
    int row = blockIdx.x / bpr, chunk = blockIdx.x % bpr;
    const float* rp = x + (size_t)row * L;
    float t1 = thr1[row];
    int o = chunk * CHUNK + threadIdx.x * EPT;

    float xv[12];   // xp1 at logical [o-2, o+10)
    if (o >= 8 && o + 16 <= L) {
        float w[24];   // x[o-8 .. o+15]
        const float4* p = reinterpret_cast<const float4*>(rp + o - 8);
        #pragma unroll
        for (int j = 0; j < 6; ++j) {
            float4 v = p[j];
            w[4*j+0] = v.x; w[4*j+1] = v.y; w[4*j+2] = v.z; w[4*j+3] = v.w;
        }
        float s5  = w[4] + w[5] + w[6] + w[7] + w[8];
        float s11 = w[1] + w[2] + w[3] + w[4] + w[5] + w[6]
                  + w[7] + w[8] + w[9] + w[10] + w[11];
        #pragma unroll
        for (int j = 0; j < 12; ++j) {
            float local = s5 * 0.2f;
            float trend = s11 * (1.0f / 11.0f);
            float r = w[6 + j] - local;
            r = (fabsf(r) > t1) ? r * C_SPIKE_D : r;
            xv[j] = (1.0f - C_TREND) * local + C_TREND * trend + C_DETAIL * r;
            if (j < 11) { s5 += w[9 + j] - w[4 + j]; s11 += w[12 + j] - w[1 + j]; }
        }
    } else {
        #pragma unroll
        for (int j = 0; j < 12; ++j) xv[j] = xp1_scalar(rp, L, o - 2 + j, t1);
    }

    double s = 0.0, s2 = 0.0;
    float t5 = xv[0] + xv[1] + xv[2] + xv[3] + xv[4];
    #pragma unroll
    for (int k = 0; k < EPT; ++k) {
        float r2 = xv[2 + k] - t5 * 0.2f;
        s += (double)r2;
        s2 = fma((double)r2, (double)r2, s2);
        if (k < EPT - 1) t5 += xv[5 + k] - xv[k];
    }
    partial_and_finalize(s, s2, partials2 + (size_t)row * bpr,
                         &cnt2[row], &thr2[row], chunk, bpr, L);
}

// ---- K3: recompute pass-1 in halo, apply pass-2, write out ----
__global__ __launch_bounds__(NTHREADS) void k3_apply(
    const float* __restrict__ x, const float* __restrict__ thr1,
    const float* __restrict__ thr2, float* __restrict__ out, int L, int bpr) {
    int row = blockIdx.x / bpr, chunk = blockIdx.x % bpr;
    const float* rp = x + (size_t)row * L;
    float* orow = out + (size_t)row * L;
    float t1 = thr1[row];
    float t2 = thr2[row];
    int o = chunk * CHUNK + threadIdx.x * EPT;

    float xv[18];   // xp1 at logical [o-5, o+13)
    if (o >= 12 && o + 20 <= L) {
        float w[32];   // x[o-12 .. o+19]
        const float4* p = reinterpret_cast<const float4*>(rp + o - 12);
        #pragma unroll
        for (int j = 0; j < 8; ++j) {
            float4 v = p[j];
            w[4*j+0] = v.x; w[4*j+1] = v.y; w[4*j+2] = v.z; w[4*j+3] = v.w;
        }
        // xv[j] at pos p=o-5+j needs x[p-5..p+5] = w[j+2 .. j+12], center w[j+7]
        float s5  = w[5] + w[6] + w[7] + w[8] + w[9];
        float s11 = w[2] + w[3] + w[4] + w[5] + w[6] + w[7]
                  + w[8] + w[9] + w[10] + w[11] + w[12];
        #pragma unroll
        for (int j = 0; j < 18; ++j) {
            float local = s5 * 0.2f;
            float trend = s11 * (1.0f / 11.0f);
            float r = w[7 + j] - local;
            r = (fabsf(r) > t1) ? r * C_SPIKE_D : r;
            xv[j] = (1.0f - C_TREND) * local + C_TREND * trend + C_DETAIL * r;
            if (j < 17) { s5 += w[10 + j] - w[5 + j]; s11 += w[13 + j] - w[2 + j]; }
        }
    } else {
        #pragma unroll
        for (int j = 0; j < 18; ++j) xv[j] = xp1_scalar(rp, L, o - 5 + j, t1);
    }

    // pass-2 apply on xv: out[o+k] from xv[k..k+10], center xv[k+5]
    float s5  = xv[3] + xv[4] + xv[5] + xv[6] + xv[7];
    float s11 = xv[0] + xv[1] + xv[2] + xv[3] + xv[4] + xv[5]
              + xv[6] + xv[7] + xv[8] + xv[9] + xv[10];
    float res[EPT];
    #pragma unroll
    for (int k = 0; k < EPT; ++k) {
        float local = s5 * 0.2f;
        float trend = s11 * (1.0f / 11.0f);
        float r = xv[5 + k] - local;
        r = (fabsf(r) > t2) ? r * C_SPIKE_D : r;
        res[k] = (1.0f - C_TREND) * local + C_TREND * trend + C_DETAIL * r;
        if (k < EPT - 1) { s5 += xv[8 + k] - xv[3 + k]; s11 += xv[11 + k] - xv[k]; }
    }
    vfloat4 r0 = { res[0], res[1], res[2], res[3] };
    vfloat4 r1 = { res[4], res[5], res[6], res[7] };
    __builtin_nontemporal_store(r0, reinterpret_cast<vfloat4*>(orow + o));
    __builtin_nontemporal_store(r1, reinterpret_cast<vfloat4*>(orow + o) + 1);
}

extern "C" void kernel_launch(void* const* d_in, const int* in_sizes, int n_in,
                              void* d_out, int out_size, void* d_ws, size_t ws_size,
                              hipStream_t stream) {
    const float* x = (const float*)d_in[0];
    float* outp = (float*)d_out;

    int total = in_sizes[0];
    int L = total / ROWS;          // 1048576
    int bpr = L / CHUNK;           // 512
    int nblocks = ROWS * bpr;      // 8192

    // workspace: [partials1][partials2][thr1][thr2][cnt]
    double2* partials1 = (double2*)d_ws;
    double2* partials2 = partials1 + nblocks;
    float* thr1 = (float*)(partials2 + nblocks);
    float* thr2 = thr1 + ROWS;
    int* cnt = (int*)(thr2 + ROWS);   // 2*ROWS ints

    (void)hipMemsetAsync(cnt, 0, 2 * ROWS * sizeof(int), stream);

    k1_reduce<<<nblocks, NTHREADS, 0, stream>>>(x, partials1, cnt, thr1, L, bpr);
    k2_reduce<<<nblocks, NTHREADS, 0, stream>>>(x, thr1, partials2, cnt + ROWS, thr2, L, bpr);
    k3_apply <<<nblocks, NTHREADS, 0, stream>>>(x, thr1, thr2, outp, L, bpr);
}

// Round 6
// 70.817 us; speedup vs baseline: 6.8632x; 6.8632x over previous
//
#include <hip/hip_runtime.h>

#define NTHREADS 256
#define EPT      8              // elements per thread per chunk
#define CHUNK    (NTHREADS*EPT) // 2048 elements
#define ROWS     16
#define BPRB     64             // blocks per row
#define NBLOCKS  (ROWS*BPRB)    // 1024

#define C_TREND   0.6f
#define C_DETAIL  0.85f
#define C_SPIKE_T 3.5f
#define C_SPIKE_D 0.35f
#define C_EPS     1e-6f

typedef float vfloat4 __attribute__((ext_vector_type(4)));

__device__ __forceinline__ float reflect_load(const float* __restrict__ rp, int g, int L) {
    if (g < 0) g = -g;
    else if (g >= L) g = 2 * L - 2 - g;
    return rp[g];
}

// Deterministic block reduce of (s,s2); totals valid in thread 0.
__device__ __forceinline__ void blk_reduce2(double& s, double& s2) {
    #pragma unroll
    for (int off = 32; off > 0; off >>= 1) {
        s  += __shfl_xor(s, off);
        s2 += __shfl_xor(s2, off);
    }
    __shared__ double lds[8];
    int wid = threadIdx.x >> 6, lane = threadIdx.x & 63;
    if (lane == 0) { lds[2*wid] = s; lds[2*wid+1] = s2; }
    __syncthreads();
    s  = lds[0] + lds[2] + lds[4] + lds[6];
    s2 = lds[1] + lds[3] + lds[5] + lds[7];
}

// All blocks of a row compute the IDENTICAL threshold: 64 double2, fixed order.
__device__ __forceinline__ float compute_thr(const double2* __restrict__ prow, int L) {
    __shared__ float thr_s;
    if (threadIdx.x < 64) {
        double2 v = prow[threadIdx.x];
        double s = v.x, s2 = v.y;
        #pragma unroll
        for (int off = 32; off > 0; off >>= 1) {
            s  += __shfl_xor(s, off);
            s2 += __shfl_xor(s2, off);
        }
        if (threadIdx.x == 0) {
            double n = (double)L;
            double var = (s2 - s * s / n) / (n - 1.0);
            float stdv = (float)sqrt(fmax(var, 0.0));
            thr_s = fmaxf(stdv, C_EPS) * C_SPIKE_T;
        }
    }
    __syncthreads();
    return thr_s;
}

// scalar (boundary) pass-1 output at logical position p (reflect-indexed)
__device__ float xp1_scalar(const float* __restrict__ rp, int L, int p, float thr) {
    if (p < 0) p = -p;
    else if (p >= L) p = 2 * L - 2 - p;
    float s5 = 0.f, s11 = 0.f;
    #pragma unroll
    for (int k = -5; k <= 5; ++k) {
        float v = reflect_load(rp, p + k, L);
        s11 += v;
        if (k >= -2 && k <= 2) s5 += v;
    }
    float local = s5 * 0.2f;
    float trend = s11 * (1.0f / 11.0f);
    float r = rp[p] - local;
    r = (fabsf(r) > thr) ? r * C_SPIKE_D : r;
    return (1.0f - C_TREND) * local + C_TREND * trend + C_DETAIL * r;
}

// ---- K1: pass-1 residual partials (8 chunks per block, plain store) ----
__global__ __launch_bounds__(NTHREADS) void k1_reduce(
    const float* __restrict__ x, double2* __restrict__ partials1, int L, int cpb) {
    int row = blockIdx.x / BPRB, cgid = blockIdx.x % BPRB;
    const float* rp = x + (size_t)row * L;
    int base = cgid * cpb;

    double s = 0.0, s2 = 0.0;
    for (int i = 0; i < cpb; ++i) {
        int o = (base + i) * CHUNK + threadIdx.x * EPT;
        float w[16];
        if (o >= 4 && o + 12 <= L) {
            const float4* p = reinterpret_cast<const float4*>(rp + o - 4);
            #pragma unroll
            for (int j = 0; j < 4; ++j) {
                float4 v = p[j];
                w[4*j+0] = v.x; w[4*j+1] = v.y; w[4*j+2] = v.z; w[4*j+3] = v.w;
            }
        } else {
            #pragma unroll
            for (int j = 0; j < 16; ++j) w[j] = reflect_load(rp, o - 4 + j, L);
        }
        float s5 = w[2] + w[3] + w[4] + w[5] + w[6];
        #pragma unroll
        for (int k = 0; k < EPT; ++k) {
            float r = w[4 + k] - s5 * 0.2f;
            s += (double)r;
            s2 = fma((double)r, (double)r, s2);
            if (k < EPT - 1) s5 += w[7 + k] - w[2 + k];
        }
    }
    blk_reduce2(s, s2);
    if (threadIdx.x == 0) partials1[blockIdx.x] = make_double2(s, s2);
}

// ---- K2: thr1 inline; recompute xp1 in-register; pass-2 residual partials ----
__global__ __launch_bounds__(NTHREADS) void k2_reduce(
    const float* __restrict__ x, const double2* __restrict__ partials1,
    double2* __restrict__ partials2, int L, int cpb) {
    int row = blockIdx.x / BPRB, cgid = blockIdx.x % BPRB;
    const float* rp = x + (size_t)row * L;
    float t1 = compute_thr(partials1 + row * BPRB, L);
    int base = cgid * cpb;

    double s = 0.0, s2 = 0.0;
    for (int i = 0; i < cpb; ++i) {
        int o = (base + i) * CHUNK + threadIdx.x * EPT;
        float xv[12];   // xp1 at logical [o-2, o+10)
        if (o >= 8 && o + 16 <= L) {
            float w[24];   // x[o-8 .. o+15]
            const float4* p = reinterpret_cast<const float4*>(rp + o - 8);
            #pragma unroll
            for (int j = 0; j < 6; ++j) {
                float4 v = p[j];
                w[4*j+0] = v.x; w[4*j+1] = v.y; w[4*j+2] = v.z; w[4*j+3] = v.w;
            }
            float s5  = w[4] + w[5] + w[6] + w[7] + w[8];
            float s11 = w[1] + w[2] + w[3] + w[4] + w[5] + w[6]
                      + w[7] + w[8] + w[9] + w[10] + w[11];
            #pragma unroll
            for (int j = 0; j < 12; ++j) {
                float local = s5 * 0.2f;
                float trend = s11 * (1.0f / 11.0f);
                float r = w[6 + j] - local;
                r = (fabsf(r) > t1) ? r * C_SPIKE_D : r;
                xv[j] = (1.0f - C_TREND) * local + C_TREND * trend + C_DETAIL * r;
                if (j < 11) { s5 += w[9 + j] - w[4 + j]; s11 += w[12 + j] - w[1 + j]; }
            }
        } else {
            #pragma unroll
            for (int j = 0; j < 12; ++j) xv[j] = xp1_scalar(rp, L, o - 2 + j, t1);
        }
        float t5 = xv[0] + xv[1] + xv[2] + xv[3] + xv[4];
        #pragma unroll
        for (int k = 0; k < EPT; ++k) {
            float r2 = xv[2 + k] - t5 * 0.2f;
            s += (double)r2;
            s2 = fma((double)r2, (double)r2, s2);
            if (k < EPT - 1) t5 += xv[5 + k] - xv[k];
        }
    }
    blk_reduce2(s, s2);
    if (threadIdx.x == 0) partials2[blockIdx.x] = make_double2(s, s2);
}

// ---- K3: thr1+thr2 inline; recompute xp1 halo; apply pass-2; write out ----
__global__ __launch_bounds__(NTHREADS) void k3_apply(
    const float* __restrict__ x, const double2* __restrict__ partials1,
    const double2* __restrict__ partials2, float* __restrict__ out, int L, int cpb) {
    int row = blockIdx.x / BPRB, cgid = blockIdx.x % BPRB;
    const float* rp = x + (size_t)row * L;
    float* orow = out + (size_t)row * L;
    float t1 = compute_thr(partials1 + row * BPRB, L);
    float t2 = compute_thr(partials2 + row * BPRB, L);
    int base = cgid * cpb;

    for (int i = 0; i < cpb; ++i) {
        int o = (base + i) * CHUNK + threadIdx.x * EPT;
        float xv[18];   // xp1 at logical [o-5, o+13)
        if (o >= 12 && o + 20 <= L) {
            float w[32];   // x[o-12 .. o+19]
            const float4* p = reinterpret_cast<const float4*>(rp + o - 12);
            #pragma unroll
            for (int j = 0; j < 8; ++j) {
                float4 v = p[j];
                w[4*j+0] = v.x; w[4*j+1] = v.y; w[4*j+2] = v.z; w[4*j+3] = v.w;
            }
            float s5  = w[5] + w[6] + w[7] + w[8] + w[9];
            float s11 = w[2] + w[3] + w[4] + w[5] + w[6] + w[7]
                      + w[8] + w[9] + w[10] + w[11] + w[12];
            #pragma unroll
            for (int j = 0; j < 18; ++j) {
                float local = s5 * 0.2f;
                float trend = s11 * (1.0f / 11.0f);
                float r = w[7 + j] - local;
                r = (fabsf(r) > t1) ? r * C_SPIKE_D : r;
                xv[j] = (1.0f - C_TREND) * local + C_TREND * trend + C_DETAIL * r;
                if (j < 17) { s5 += w[10 + j] - w[5 + j]; s11 += w[13 + j] - w[2 + j]; }
            }
        } else {
            #pragma unroll
            for (int j = 0; j < 18; ++j) xv[j] = xp1_scalar(rp, L, o - 5 + j, t1);
        }

        float s5  = xv[3] + xv[4] + xv[5] + xv[6] + xv[7];
        float s11 = xv[0] + xv[1] + xv[2] + xv[3] + xv[4] + xv[5]
                  + xv[6] + xv[7] + xv[8] + xv[9] + xv[10];
        float res[EPT];
        #pragma unroll
        for (int k = 0; k < EPT; ++k) {
            float local = s5 * 0.2f;
            float trend = s11 * (1.0f / 11.0f);
            float r = xv[5 + k] - local;
            r = (fabsf(r) > t2) ? r * C_SPIKE_D : r;
            res[k] = (1.0f - C_TREND) * local + C_TREND * trend + C_DETAIL * r;
            if (k < EPT - 1) { s5 += xv[8 + k] - xv[3 + k]; s11 += xv[11 + k] - xv[k]; }
        }
        vfloat4 r0 = { res[0], res[1], res[2], res[3] };
        vfloat4 r1 = { res[4], res[5], res[6], res[7] };
        __builtin_nontemporal_store(r0, reinterpret_cast<vfloat4*>(orow + o));
        __builtin_nontemporal_store(r1, reinterpret_cast<vfloat4*>(orow + o) + 1);
    }
}

extern "C" void kernel_launch(void* const* d_in, const int* in_sizes, int n_in,
                              void* d_out, int out_size, void* d_ws, size_t ws_size,
                              hipStream_t stream) {
    const float* x = (const float*)d_in[0];
    float* outp = (float*)d_out;

    int total = in_sizes[0];
    int L = total / ROWS;          // 1048576
    int bpr = L / CHUNK;           // 512 chunks per row
    int cpb = bpr / BPRB;          // 8 chunks per block

    // workspace: [partials1 16KB][partials2 16KB]
    double2* partials1 = (double2*)d_ws;
    double2* partials2 = partials1 + NBLOCKS;

    k1_reduce<<<NBLOCKS, NTHREADS, 0, stream>>>(x, partials1, L, cpb);
    k2_reduce<<<NBLOCKS, NTHREADS, 0, stream>>>(x, partials1, partials2, L, cpb);
    k3_apply <<<NBLOCKS, NTHREADS, 0, stream>>>(x, partials1, partials2, outp, L, cpb);
}